// Round 6
// baseline (163.588 us; speedup 1.0000x reference)
//
#include <hip/hip_runtime.h>
#include <math.h>

// Gaussian splatting forward renderer, MI355X — R5: 2 dispatches total.
//  K1 gs_preprocess : per-gaussian params + depth key -> ws; per-BLOCK key
//                     min / min-of-complement -> MMpart (no atomics/memset);
//                     block 0 zeroes the 64 per-tile tickets.
//  K2 gs_render     : grid (16 depth-buckets x 64 tiles) x 256 thr.
//                     Phase 0: every block reduces MMpart -> identical
//                              global dmin/dmax (uniform scalar loads).
//                     Phase 1: scan all N, keep bbox ∩ depth-bucket survivors.
//                     Phase 2: rank sort (~24-60 entries) in LDS.
//                     Phase 3: front-to-back blend -> per-pixel partials.
//                     Phase 4: write partials, __threadfence (device scope),
//                              ticket atomicAdd; LAST block per tile acquires,
//                              ordered-combines 16 buckets + white bkgd -> out.
// Buckets are depth RANGES => concatenation == exact reference depth order
// (same reassociation structure validated since R1, absmax 0.0156 << 0.255).

#define NMAX 8192
#define TPB 256
#define NSEGD 16
#define CAP 768    // per-(tile,bucket) survivor capacity (expected ~24-100)

__device__ __forceinline__ float keyToDepth(unsigned k) {
    unsigned bits = (k & 0x80000000u) ? (k & 0x7FFFFFFFu) : ~k;
    return __uint_as_float(bits);
}

__global__ __launch_bounds__(TPB) void gs_preprocess(
    const float* __restrict__ means3D, const float* __restrict__ opacity,
    const float* __restrict__ scales, const float* __restrict__ rotations,
    const float* __restrict__ shs, const float* __restrict__ viewmatrix,
    const float* __restrict__ projmatrix, const float* __restrict__ camcenter,
    float4* __restrict__ A, float4* __restrict__ B, float4* __restrict__ C,
    float4* __restrict__ D, unsigned* __restrict__ K,
    unsigned* __restrict__ MMpart, int* __restrict__ tickets, int N)
{
    const int tid = threadIdx.x;
    const int i = blockIdx.x * blockDim.x + tid;
    const bool valid = (i < N);

    unsigned kb = 0xFFFFFFFFu, nkb = 0xFFFFFFFFu;

    if (valid) {
        float V[16], P[16];
#pragma unroll
        for (int k = 0; k < 16; ++k) V[k] = viewmatrix[k];
#pragma unroll
        for (int k = 0; k < 16; ++k) P[k] = projmatrix[k];

        float mx = means3D[3*i+0], my = means3D[3*i+1], mz = means3D[3*i+2];

        float pv0 = mx*V[0] + my*V[4] + mz*V[8]  + V[12];
        float pv1 = mx*V[1] + my*V[5] + mz*V[9]  + V[13];
        float pv2 = mx*V[2] + my*V[6] + mz*V[10] + V[14];
        float pv3 = mx*V[3] + my*V[7] + mz*V[11] + V[15];

        float ph0 = pv0*P[0] + pv1*P[4] + pv2*P[8]  + pv3*P[12];
        float ph1 = pv0*P[1] + pv1*P[5] + pv2*P[9]  + pv3*P[13];
        float ph3 = pv0*P[3] + pv1*P[7] + pv2*P[11] + pv3*P[15];
        float invw = 1.0f / (ph3 + 1e-6f);
        float ppx = ph0 * invw, ppy = ph1 * invw;
        float depth = pv2;

        // SH deg 3, dirs = means3D - camera_center (unnormalized, per ref)
        float rdx = mx - camcenter[0], rdy = my - camcenter[1], rdz = mz - camcenter[2];
        float xx = rdx*rdx, yy = rdy*rdy, zz = rdz*rdz;
        float xy = rdx*rdy, yz = rdy*rdz, xz = rdx*rdz;
        const float C0 = 0.28209479177387814f;
        const float C1 = 0.4886025119029199f;
        const float C2_0 =  1.0925484305920792f, C2_1 = -1.0925484305920792f,
                    C2_2 =  0.31539156525252005f, C2_3 = -1.0925484305920792f,
                    C2_4 =  0.5462742152960396f;
        const float C3_0 = -0.5900435899266435f, C3_1 = 2.890611442640554f,
                    C3_2 = -0.4570457994644658f, C3_3 = 0.3731763325901154f,
                    C3_4 = -0.4570457994644658f, C3_5 = 1.445305721320277f,
                    C3_6 = -0.5900435899266435f;
        float col[3];
#pragma unroll
        for (int c = 0; c < 3; ++c) {
            const float* sh = shs + (size_t)i*48 + c;
            float res = C0*sh[0]
                - C1*rdy*sh[3] + C1*rdz*sh[6] - C1*rdx*sh[9]
                + C2_0*xy*sh[12] + C2_1*yz*sh[15] + C2_2*(2.f*zz-xx-yy)*sh[18]
                + C2_3*xz*sh[21] + C2_4*(xx-yy)*sh[24]
                + C3_0*rdy*(3.f*xx-yy)*sh[27] + C3_1*xy*rdz*sh[30]
                + C3_2*rdy*(4.f*zz-xx-yy)*sh[33] + C3_3*rdz*(2.f*zz-3.f*xx-3.f*yy)*sh[36]
                + C3_4*rdx*(4.f*zz-xx-yy)*sh[39] + C3_5*rdz*(xx-yy)*sh[42]
                + C3_6*rdx*(xx-3.f*yy)*sh[45];
            col[c] = fmaxf(res + 0.5f, 0.0f);
        }

        // cov3d
        float qr = rotations[4*i+0], qx = rotations[4*i+1], qy = rotations[4*i+2], qz = rotations[4*i+3];
        float qn = sqrtf(qr*qr + qx*qx + qy*qy + qz*qz);
        qr /= qn; qx /= qn; qy /= qn; qz /= qn;
        float R00 = 1.f - 2.f*(qy*qy + qz*qz), R01 = 2.f*(qx*qy - qr*qz), R02 = 2.f*(qx*qz + qr*qy);
        float R10 = 2.f*(qx*qy + qr*qz), R11 = 1.f - 2.f*(qx*qx + qz*qz), R12 = 2.f*(qy*qz - qr*qx);
        float R20 = 2.f*(qx*qz - qr*qy), R21 = 2.f*(qy*qz + qr*qx), R22 = 1.f - 2.f*(qx*qx + qy*qy);
        float s0 = scales[3*i+0], s1 = scales[3*i+1], s2 = scales[3*i+2];
        float L00=R00*s0, L01=R01*s1, L02=R02*s2;
        float L10=R10*s0, L11=R11*s1, L12=R12*s2;
        float L20=R20*s0, L21=R21*s1, L22=R22*s2;
        float c300=L00*L00+L01*L01+L02*L02;
        float c301=L00*L10+L01*L11+L02*L12;
        float c302=L00*L20+L01*L21+L02*L22;
        float c311=L10*L10+L11*L11+L12*L12;
        float c312=L10*L20+L11*L21+L12*L22;
        float c322=L20*L20+L21*L21+L22*L22;

        // EWA projection
        const float TANX = 0.5773502691896257f;
        const float FX = 128.0f / (2.0f * TANX);
        float tz = pv2;
        float limx = 1.3f * TANX;
        float txv = fminf(fmaxf(pv0 / tz, -limx), limx) * tz;
        float tyv = fminf(fmaxf(pv1 / tz, -limx), limx) * tz;
        float j00 = FX / tz, j02 = -txv * FX / (tz*tz);
        float j11 = FX / tz, j12 = -tyv * FX / (tz*tz);

        float Wm00=V[0], Wm01=V[4], Wm02=V[8];
        float Wm10=V[1], Wm11=V[5], Wm12=V[9];
        float Wm20=V[2], Wm21=V[6], Wm22=V[10];

        float t00 = Wm00*c300 + Wm01*c301 + Wm02*c302;
        float t01 = Wm00*c301 + Wm01*c311 + Wm02*c312;
        float t02 = Wm00*c302 + Wm01*c312 + Wm02*c322;
        float t10 = Wm10*c300 + Wm11*c301 + Wm12*c302;
        float t11 = Wm10*c301 + Wm11*c311 + Wm12*c312;
        float t12 = Wm10*c302 + Wm11*c312 + Wm12*c322;
        float t20 = Wm20*c300 + Wm21*c301 + Wm22*c302;
        float t21 = Wm20*c301 + Wm21*c311 + Wm22*c312;
        float t22 = Wm20*c302 + Wm21*c312 + Wm22*c322;
        float M00 = t00*Wm00 + t01*Wm01 + t02*Wm02;
        float M01 = t00*Wm10 + t01*Wm11 + t02*Wm12;
        float M02 = t00*Wm20 + t01*Wm21 + t02*Wm22;
        float M11 = t10*Wm10 + t11*Wm11 + t12*Wm12;
        float M12 = t10*Wm20 + t11*Wm21 + t12*Wm22;
        float M21 = t20*Wm10 + t21*Wm11 + t22*Wm12;
        float M20 = t20*Wm00 + t21*Wm01 + t22*Wm02;
        float M22 = t20*Wm20 + t21*Wm21 + t22*Wm22;

        float JM00 = j00*M00 + j02*M20;
        float JM01 = j00*M01 + j02*M21;
        float JM02 = j00*M02 + j02*M22;
        float JM11 = j11*M11 + j12*M21;
        float JM12 = j11*M12 + j12*M22;
        float a = JM00*j00 + JM02*j02 + 0.3f;
        float b = JM01*j11 + JM02*j12;
        float d = JM11*j11 + JM12*j12 + 0.3f;

        float m2x = ((ppx + 1.0f)*128.0f - 1.0f)*0.5f;
        float m2y = ((ppy + 1.0f)*128.0f - 1.0f)*0.5f;

        float det = a*d - b*b;
        float mid = 0.5f*(a + d);
        float sq = sqrtf(fmaxf(mid*mid - det, 0.1f));
        float radii = 3.0f * ceilf(sqrtf(fmaxf(mid + sq, mid - sq)));
        float rminx = fminf(fmaxf(m2x - radii, 0.0f), 127.0f);
        float rminy = fminf(fmaxf(m2y - radii, 0.0f), 127.0f);
        float rmaxx = fminf(fmaxf(m2x + radii, 0.0f), 127.0f);
        float rmaxy = fminf(fmaxf(m2y + radii, 0.0f), 127.0f);

        float idet = 1.0f / det;
        float c00i = d*idet, c11i = a*idet, cxyi = -2.0f*b*idet;

        kb = __float_as_uint(depth);
        kb = (kb & 0x80000000u) ? ~kb : (kb | 0x80000000u);
        nkb = ~kb;

        K[i] = kb;
        A[i] = make_float4(m2x, m2y, c00i, c11i);
        B[i] = make_float4(cxyi, opacity[i], depth, 0.0f);
        C[i] = make_float4(col[0], col[1], col[2], 0.0f);
        D[i] = make_float4(rminx, rminy, rmaxx, rmaxy);
    }

    // per-block min reduce of kb and ~kb (=> global max)
    __shared__ unsigned s_r0[TPB], s_r1[TPB];
    s_r0[tid] = kb; s_r1[tid] = nkb;
    __syncthreads();
    for (int off = TPB/2; off > 0; off >>= 1) {
        if (tid < off) {
            s_r0[tid] = min(s_r0[tid], s_r0[tid + off]);
            s_r1[tid] = min(s_r1[tid], s_r1[tid + off]);
        }
        __syncthreads();
    }
    if (tid == 0) {
        MMpart[2*blockIdx.x]   = s_r0[0];
        MMpart[2*blockIdx.x+1] = s_r1[0];
    }
    if (blockIdx.x == 0 && tid < 64) tickets[tid] = 0;  // reset every call
}

// grid (NSEGD buckets, 64 tiles) x 256 thr; last block per tile combines.
__global__ __launch_bounds__(TPB) void gs_render(
    const float4* __restrict__ A, const float4* __restrict__ B,
    const float4* __restrict__ C, const float4* __restrict__ D,
    const unsigned* __restrict__ K, const unsigned* __restrict__ MMpart,
    int* __restrict__ tickets,
    float4* __restrict__ P1, float2* __restrict__ P2,
    float* __restrict__ out, int N, int nblk)
{
    __shared__ unsigned long long s_keys[CAP];
    __shared__ unsigned s_sorted[CAP];
    __shared__ float4 sA[TPB], sB[TPB], sC[TPB];
    __shared__ int s_count;
    __shared__ int s_ticket;

    const int tid = threadIdx.x;
    const int seg = blockIdx.x;
    const int tile = blockIdx.y;
    const int h = (tile >> 3) * 16;
    const int w = (tile & 7) * 16;
    const float fw = (float)w, fh = (float)h;

    // Phase 0: reduce per-block minima (uniform addresses -> scalar loads;
    // every block computes the IDENTICAL dmin/dmax deterministically).
    unsigned kmin = 0xFFFFFFFFu, nkmin = 0xFFFFFFFFu;
    for (int bidx = 0; bidx < nblk; ++bidx) {
        kmin  = min(kmin,  MMpart[2*bidx]);
        nkmin = min(nkmin, MMpart[2*bidx+1]);
    }
    const float dmin = keyToDepth(kmin);
    const float dmax = keyToDepth(~nkmin);
    const float scale = (float)NSEGD / fmaxf(dmax - dmin, 1e-20f);

    if (tid == 0) s_count = 0;
    __syncthreads();

    // Phase 1: scan all gaussians; keep bbox ∩ depth-bucket survivors
    for (int g = tid; g < N; g += TPB) {
        float4 d4 = D[g];
        float tlx = fmaxf(d4.x, fw), tly = fmaxf(d4.y, fh);
        float brx = fminf(d4.z, fw + 15.0f), bry = fminf(d4.w, fh + 15.0f);
        if (brx > tlx && bry > tly) {
            unsigned kb = K[g];
            float depth = keyToDepth(kb);
            int sg = (int)((depth - dmin) * scale);
            sg = sg < 0 ? 0 : (sg > NSEGD-1 ? NSEGD-1 : sg);
            if (sg == seg) {
                int pos = atomicAdd(&s_count, 1);
                if (pos < CAP)
                    s_keys[pos] = (((unsigned long long)kb) << 32) | (unsigned)g;
            }
        }
    }
    __syncthreads();
    int cnt = s_count; cnt = cnt > CAP ? CAP : cnt;

    // Phase 2: rank sort (unique composite keys => stable depth argsort)
    for (int s = tid; s < cnt; s += TPB) {
        unsigned long long my = s_keys[s];
        int r = 0;
        for (int j = 0; j < cnt; ++j) r += (s_keys[j] < my);
        s_sorted[r] = (unsigned)(my & 0xffffffffu);
    }
    __syncthreads();

    // Phase 3: front-to-back blend of this bucket
    const int pxi = tid & 15, pyi = tid >> 4;
    const float px = (float)(w + pxi), py = (float)(h + pyi);
    float T = 1.0f, cr = 0.f, cg = 0.f, cb = 0.f, dp = 0.f, ac = 0.f;

    for (int base = 0; base < cnt; base += TPB) {
        int m = min(TPB, cnt - base);
        if (base) __syncthreads();
        if (tid < m) {
            int g = (int)s_sorted[base + tid];
            sA[tid] = A[g]; sB[tid] = B[g]; sC[tid] = C[g];
        }
        __syncthreads();
        for (int jj = 0; jj < m; ++jj) {
            float4 a4 = sA[jj], b4 = sB[jj], c4 = sC[jj];
            float ddx = px - a4.x, ddy = py - a4.y;
            float power = -0.5f * (ddx*ddx*a4.z + ddy*ddy*a4.w + ddx*ddy*b4.x);
            float alpha = fminf(__expf(power) * b4.y, 0.99f);
            float wgt = alpha * T;
            cr += wgt * c4.x; cg += wgt * c4.y; cb += wgt * c4.z;
            dp += wgt * b4.z; ac += wgt;
            T *= (1.0f - alpha);
        }
    }

    // Phase 4: publish partials; last block per tile combines.
    const int pidx = (seg * 64 + tile) * TPB + tid;
    P1[pidx] = make_float4(cr, cg, cb, dp);
    P2[pidx] = make_float2(ac, T);
    __threadfence();                 // release partials (device scope)
    __syncthreads();                 // whole block done before taking ticket
    if (tid == 0) s_ticket = atomicAdd(&tickets[tile], 1);
    __syncthreads();
    if (s_ticket == NSEGD - 1) {
        __threadfence();             // acquire other blocks' partials
        float Tpre = 1.0f, CR = 0.f, CG = 0.f, CB = 0.f, DP = 0.f, AC = 0.f;
#pragma unroll
        for (int s = 0; s < NSEGD; ++s) {
            const int idx = (s * 64 + tile) * TPB + tid;
            float4 p1 = P1[idx];
            float2 p2 = P2[idx];
            CR += Tpre * p1.x; CG += Tpre * p1.y; CB += Tpre * p1.z;
            DP += Tpre * p1.w; AC += Tpre * p2.x;
            Tpre *= p2.y;
        }
        CR += (1.0f - AC); CG += (1.0f - AC); CB += (1.0f - AC);

        const int y = h + pyi, x = w + pxi;
        const int pix = y * 128 + x;
        out[pix*3 + 0] = CR;
        out[pix*3 + 1] = CG;
        out[pix*3 + 2] = CB;
        out[128*128*3 + pix] = DP;
        out[128*128*3 + 128*128 + pix] = AC;
    }
}

extern "C" void kernel_launch(void* const* d_in, const int* in_sizes, int n_in,
                              void* d_out, int out_size, void* d_ws, size_t ws_size,
                              hipStream_t stream) {
    const float* means3D    = (const float*)d_in[0];
    const float* opacity    = (const float*)d_in[1];
    const float* scales     = (const float*)d_in[2];
    const float* rotations  = (const float*)d_in[3];
    const float* shs        = (const float*)d_in[4];
    const float* viewmatrix = (const float*)d_in[5];
    const float* projmatrix = (const float*)d_in[6];
    const float* camcenter  = (const float*)d_in[7];
    float* out = (float*)d_out;

    int N = in_sizes[0] / 3;   // 8192
    int nblk = (N + TPB - 1) / TPB;

    char* p = (char*)d_ws;
    float4* A = (float4*)p;          p += (size_t)NMAX * sizeof(float4);
    float4* B = (float4*)p;          p += (size_t)NMAX * sizeof(float4);
    float4* C = (float4*)p;          p += (size_t)NMAX * sizeof(float4);
    float4* D = (float4*)p;          p += (size_t)NMAX * sizeof(float4);
    float4* P1 = (float4*)p;         p += (size_t)NSEGD * 64 * TPB * sizeof(float4);
    float2* P2 = (float2*)p;         p += (size_t)NSEGD * 64 * TPB * sizeof(float2);
    unsigned* K = (unsigned*)p;      p += (size_t)NMAX * sizeof(unsigned);
    unsigned* MMpart = (unsigned*)p; p += (size_t)2 * nblk * sizeof(unsigned);
    int* tickets = (int*)p;          p += 64 * sizeof(int);

    gs_preprocess<<<nblk, TPB, 0, stream>>>(
        means3D, opacity, scales, rotations, shs, viewmatrix, projmatrix,
        camcenter, A, B, C, D, K, MMpart, tickets, N);

    gs_render<<<dim3(NSEGD, 64), TPB, 0, stream>>>(
        A, B, C, D, K, MMpart, tickets, P1, P2, out, N, nblk);
}

// Round 7
// 42.246 us; speedup vs baseline: 3.8723x; 3.8723x over previous
//
#include <hip/hip_runtime.h>
#include <math.h>

// Gaussian splatting forward renderer, MI355X — R6: 3 dispatches, no fences.
//  K1 gs_preprocess : per-gaussian params + depth key -> ws; per-BLOCK key
//                     min / min-of-complement -> MMpart (no atomics, no memset).
//  K2 gs_render     : grid (16 depth-buckets x 64 tiles) x 256 thr.
//                     Phase 0: every block reduces MMpart -> identical global
//                              dmin/dmax (order-independent min => exact).
//                     Phase 1: scan all N, keep bbox ∩ depth-bucket survivors.
//                     Phase 2: rank sort (~44 entries) in LDS.
//                     Phase 3: front-to-back blend -> per-pixel partials P1/P2.
//  K3 gs_combine    : ordered prefix-combine of the 16 buckets + white bkgd.
// Kernel boundaries provide cross-block coherence (R5 lesson: per-block
// device-scope fences serialize chip-wide, ~150 µs for 1024 blocks).
// Buckets are depth RANGES => concatenation == exact reference depth order
// (same reassociation structure validated since R1, absmax 0.0156 << 0.255).

#define NMAX 8192
#define TPB 256
#define NSEGD 16
#define CAP 1024   // per-(tile,bucket) survivor capacity (expected ~44)

__device__ __forceinline__ float keyToDepth(unsigned k) {
    unsigned bits = (k & 0x80000000u) ? (k & 0x7FFFFFFFu) : ~k;
    return __uint_as_float(bits);
}

__global__ __launch_bounds__(TPB) void gs_preprocess(
    const float* __restrict__ means3D, const float* __restrict__ opacity,
    const float* __restrict__ scales, const float* __restrict__ rotations,
    const float* __restrict__ shs, const float* __restrict__ viewmatrix,
    const float* __restrict__ projmatrix, const float* __restrict__ camcenter,
    float4* __restrict__ A, float4* __restrict__ B, float4* __restrict__ C,
    float4* __restrict__ D, unsigned* __restrict__ K,
    unsigned* __restrict__ MMpart, int N)
{
    const int tid = threadIdx.x;
    const int i = blockIdx.x * blockDim.x + tid;
    const bool valid = (i < N);

    unsigned kb = 0xFFFFFFFFu, nkb = 0xFFFFFFFFu;

    if (valid) {
        float V[16], P[16];
#pragma unroll
        for (int k = 0; k < 16; ++k) V[k] = viewmatrix[k];
#pragma unroll
        for (int k = 0; k < 16; ++k) P[k] = projmatrix[k];

        float mx = means3D[3*i+0], my = means3D[3*i+1], mz = means3D[3*i+2];

        float pv0 = mx*V[0] + my*V[4] + mz*V[8]  + V[12];
        float pv1 = mx*V[1] + my*V[5] + mz*V[9]  + V[13];
        float pv2 = mx*V[2] + my*V[6] + mz*V[10] + V[14];
        float pv3 = mx*V[3] + my*V[7] + mz*V[11] + V[15];

        float ph0 = pv0*P[0] + pv1*P[4] + pv2*P[8]  + pv3*P[12];
        float ph1 = pv0*P[1] + pv1*P[5] + pv2*P[9]  + pv3*P[13];
        float ph3 = pv0*P[3] + pv1*P[7] + pv2*P[11] + pv3*P[15];
        float invw = 1.0f / (ph3 + 1e-6f);
        float ppx = ph0 * invw, ppy = ph1 * invw;
        float depth = pv2;

        // SH deg 3, dirs = means3D - camera_center (unnormalized, per ref)
        float rdx = mx - camcenter[0], rdy = my - camcenter[1], rdz = mz - camcenter[2];
        float xx = rdx*rdx, yy = rdy*rdy, zz = rdz*rdz;
        float xy = rdx*rdy, yz = rdy*rdz, xz = rdx*rdz;
        const float C0 = 0.28209479177387814f;
        const float C1 = 0.4886025119029199f;
        const float C2_0 =  1.0925484305920792f, C2_1 = -1.0925484305920792f,
                    C2_2 =  0.31539156525252005f, C2_3 = -1.0925484305920792f,
                    C2_4 =  0.5462742152960396f;
        const float C3_0 = -0.5900435899266435f, C3_1 = 2.890611442640554f,
                    C3_2 = -0.4570457994644658f, C3_3 = 0.3731763325901154f,
                    C3_4 = -0.4570457994644658f, C3_5 = 1.445305721320277f,
                    C3_6 = -0.5900435899266435f;
        float col[3];
#pragma unroll
        for (int c = 0; c < 3; ++c) {
            const float* sh = shs + (size_t)i*48 + c;
            float res = C0*sh[0]
                - C1*rdy*sh[3] + C1*rdz*sh[6] - C1*rdx*sh[9]
                + C2_0*xy*sh[12] + C2_1*yz*sh[15] + C2_2*(2.f*zz-xx-yy)*sh[18]
                + C2_3*xz*sh[21] + C2_4*(xx-yy)*sh[24]
                + C3_0*rdy*(3.f*xx-yy)*sh[27] + C3_1*xy*rdz*sh[30]
                + C3_2*rdy*(4.f*zz-xx-yy)*sh[33] + C3_3*rdz*(2.f*zz-3.f*xx-3.f*yy)*sh[36]
                + C3_4*rdx*(4.f*zz-xx-yy)*sh[39] + C3_5*rdz*(xx-yy)*sh[42]
                + C3_6*rdx*(xx-3.f*yy)*sh[45];
            col[c] = fmaxf(res + 0.5f, 0.0f);
        }

        // cov3d
        float qr = rotations[4*i+0], qx = rotations[4*i+1], qy = rotations[4*i+2], qz = rotations[4*i+3];
        float qn = sqrtf(qr*qr + qx*qx + qy*qy + qz*qz);
        qr /= qn; qx /= qn; qy /= qn; qz /= qn;
        float R00 = 1.f - 2.f*(qy*qy + qz*qz), R01 = 2.f*(qx*qy - qr*qz), R02 = 2.f*(qx*qz + qr*qy);
        float R10 = 2.f*(qx*qy + qr*qz), R11 = 1.f - 2.f*(qx*qx + qz*qz), R12 = 2.f*(qy*qz - qr*qx);
        float R20 = 2.f*(qx*qz - qr*qy), R21 = 2.f*(qy*qz + qr*qx), R22 = 1.f - 2.f*(qx*qx + qy*qy);
        float s0 = scales[3*i+0], s1 = scales[3*i+1], s2 = scales[3*i+2];
        float L00=R00*s0, L01=R01*s1, L02=R02*s2;
        float L10=R10*s0, L11=R11*s1, L12=R12*s2;
        float L20=R20*s0, L21=R21*s1, L22=R22*s2;
        float c300=L00*L00+L01*L01+L02*L02;
        float c301=L00*L10+L01*L11+L02*L12;
        float c302=L00*L20+L01*L21+L02*L22;
        float c311=L10*L10+L11*L11+L12*L12;
        float c312=L10*L20+L11*L21+L12*L22;
        float c322=L20*L20+L21*L21+L22*L22;

        // EWA projection
        const float TANX = 0.5773502691896257f;
        const float FX = 128.0f / (2.0f * TANX);
        float tz = pv2;
        float limx = 1.3f * TANX;
        float txv = fminf(fmaxf(pv0 / tz, -limx), limx) * tz;
        float tyv = fminf(fmaxf(pv1 / tz, -limx), limx) * tz;
        float j00 = FX / tz, j02 = -txv * FX / (tz*tz);
        float j11 = FX / tz, j12 = -tyv * FX / (tz*tz);

        float Wm00=V[0], Wm01=V[4], Wm02=V[8];
        float Wm10=V[1], Wm11=V[5], Wm12=V[9];
        float Wm20=V[2], Wm21=V[6], Wm22=V[10];

        float t00 = Wm00*c300 + Wm01*c301 + Wm02*c302;
        float t01 = Wm00*c301 + Wm01*c311 + Wm02*c312;
        float t02 = Wm00*c302 + Wm01*c312 + Wm02*c322;
        float t10 = Wm10*c300 + Wm11*c301 + Wm12*c302;
        float t11 = Wm10*c301 + Wm11*c311 + Wm12*c312;
        float t12 = Wm10*c302 + Wm11*c312 + Wm12*c322;
        float t20 = Wm20*c300 + Wm21*c301 + Wm22*c302;
        float t21 = Wm20*c301 + Wm21*c311 + Wm22*c312;
        float t22 = Wm20*c302 + Wm21*c312 + Wm22*c322;
        float M00 = t00*Wm00 + t01*Wm01 + t02*Wm02;
        float M01 = t00*Wm10 + t01*Wm11 + t02*Wm12;
        float M02 = t00*Wm20 + t01*Wm21 + t02*Wm22;
        float M11 = t10*Wm10 + t11*Wm11 + t12*Wm12;
        float M12 = t10*Wm20 + t11*Wm21 + t12*Wm22;
        float M21 = t20*Wm10 + t21*Wm11 + t22*Wm12;
        float M20 = t20*Wm00 + t21*Wm01 + t22*Wm02;
        float M22 = t20*Wm20 + t21*Wm21 + t22*Wm22;

        float JM00 = j00*M00 + j02*M20;
        float JM01 = j00*M01 + j02*M21;
        float JM02 = j00*M02 + j02*M22;
        float JM11 = j11*M11 + j12*M21;
        float JM12 = j11*M12 + j12*M22;
        float a = JM00*j00 + JM02*j02 + 0.3f;
        float b = JM01*j11 + JM02*j12;
        float d = JM11*j11 + JM12*j12 + 0.3f;

        float m2x = ((ppx + 1.0f)*128.0f - 1.0f)*0.5f;
        float m2y = ((ppy + 1.0f)*128.0f - 1.0f)*0.5f;

        float det = a*d - b*b;
        float mid = 0.5f*(a + d);
        float sq = sqrtf(fmaxf(mid*mid - det, 0.1f));
        float radii = 3.0f * ceilf(sqrtf(fmaxf(mid + sq, mid - sq)));
        float rminx = fminf(fmaxf(m2x - radii, 0.0f), 127.0f);
        float rminy = fminf(fmaxf(m2y - radii, 0.0f), 127.0f);
        float rmaxx = fminf(fmaxf(m2x + radii, 0.0f), 127.0f);
        float rmaxy = fminf(fmaxf(m2y + radii, 0.0f), 127.0f);

        float idet = 1.0f / det;
        float c00i = d*idet, c11i = a*idet, cxyi = -2.0f*b*idet;

        kb = __float_as_uint(depth);
        kb = (kb & 0x80000000u) ? ~kb : (kb | 0x80000000u);
        nkb = ~kb;

        K[i] = kb;
        A[i] = make_float4(m2x, m2y, c00i, c11i);
        B[i] = make_float4(cxyi, opacity[i], depth, 0.0f);
        C[i] = make_float4(col[0], col[1], col[2], 0.0f);
        D[i] = make_float4(rminx, rminy, rmaxx, rmaxy);
    }

    // per-block min reduce of kb and ~kb (=> global max); order-independent
    __shared__ unsigned s_r0[TPB], s_r1[TPB];
    s_r0[tid] = kb; s_r1[tid] = nkb;
    __syncthreads();
    for (int off = TPB/2; off > 0; off >>= 1) {
        if (tid < off) {
            s_r0[tid] = min(s_r0[tid], s_r0[tid + off]);
            s_r1[tid] = min(s_r1[tid], s_r1[tid + off]);
        }
        __syncthreads();
    }
    if (tid == 0) {
        MMpart[2*blockIdx.x]   = s_r0[0];
        MMpart[2*blockIdx.x+1] = s_r1[0];
    }
}

// grid (NSEGD buckets, 64 tiles) x 256 thr: partials only, no fences.
__global__ __launch_bounds__(TPB) void gs_render(
    const float4* __restrict__ A, const float4* __restrict__ B,
    const float4* __restrict__ C, const float4* __restrict__ D,
    const unsigned* __restrict__ K, const unsigned* __restrict__ MMpart,
    float4* __restrict__ P1, float2* __restrict__ P2, int N, int nblk)
{
    __shared__ unsigned long long s_keys[CAP];
    __shared__ unsigned s_sorted[CAP];
    __shared__ float4 sA[TPB], sB[TPB], sC[TPB];
    __shared__ int s_count;

    const int tid = threadIdx.x;
    const int seg = blockIdx.x;
    const int tile = blockIdx.y;
    const int h = (tile >> 3) * 16;
    const int w = (tile & 7) * 16;
    const float fw = (float)w, fh = (float)h;

    // Phase 0: reduce per-block minima (identical result in every block)
    unsigned kmin = 0xFFFFFFFFu, nkmin = 0xFFFFFFFFu;
    for (int bidx = 0; bidx < nblk; ++bidx) {
        kmin  = min(kmin,  MMpart[2*bidx]);
        nkmin = min(nkmin, MMpart[2*bidx+1]);
    }
    const float dmin = keyToDepth(kmin);
    const float dmax = keyToDepth(~nkmin);
    const float scale = (float)NSEGD / fmaxf(dmax - dmin, 1e-20f);

    if (tid == 0) s_count = 0;
    __syncthreads();

    // Phase 1: scan all gaussians; keep bbox ∩ depth-bucket survivors
    for (int g = tid; g < N; g += TPB) {
        float4 d4 = D[g];
        float tlx = fmaxf(d4.x, fw), tly = fmaxf(d4.y, fh);
        float brx = fminf(d4.z, fw + 15.0f), bry = fminf(d4.w, fh + 15.0f);
        if (brx > tlx && bry > tly) {
            unsigned kb = K[g];
            float depth = keyToDepth(kb);
            int sg = (int)((depth - dmin) * scale);
            sg = sg < 0 ? 0 : (sg > NSEGD-1 ? NSEGD-1 : sg);
            if (sg == seg) {
                int pos = atomicAdd(&s_count, 1);
                if (pos < CAP)
                    s_keys[pos] = (((unsigned long long)kb) << 32) | (unsigned)g;
            }
        }
    }
    __syncthreads();
    int cnt = s_count; cnt = cnt > CAP ? CAP : cnt;

    // Phase 2: rank sort (unique composite keys => stable depth argsort)
    for (int s = tid; s < cnt; s += TPB) {
        unsigned long long my = s_keys[s];
        int r = 0;
        for (int j = 0; j < cnt; ++j) r += (s_keys[j] < my);
        s_sorted[r] = (unsigned)(my & 0xffffffffu);
    }
    __syncthreads();

    // Phase 3: front-to-back blend of this bucket
    const int pxi = tid & 15, pyi = tid >> 4;
    const float px = (float)(w + pxi), py = (float)(h + pyi);
    float T = 1.0f, cr = 0.f, cg = 0.f, cb = 0.f, dp = 0.f, ac = 0.f;

    for (int base = 0; base < cnt; base += TPB) {
        int m = min(TPB, cnt - base);
        if (base) __syncthreads();
        if (tid < m) {
            int g = (int)s_sorted[base + tid];
            sA[tid] = A[g]; sB[tid] = B[g]; sC[tid] = C[g];
        }
        __syncthreads();
        for (int jj = 0; jj < m; ++jj) {
            float4 a4 = sA[jj], b4 = sB[jj], c4 = sC[jj];
            float ddx = px - a4.x, ddy = py - a4.y;
            float power = -0.5f * (ddx*ddx*a4.z + ddy*ddy*a4.w + ddx*ddy*b4.x);
            float alpha = fminf(__expf(power) * b4.y, 0.99f);
            float wgt = alpha * T;
            cr += wgt * c4.x; cg += wgt * c4.y; cb += wgt * c4.z;
            dp += wgt * b4.z; ac += wgt;
            T *= (1.0f - alpha);
        }
    }

    const int pidx = (seg * 64 + tile) * TPB + tid;
    P1[pidx] = make_float4(cr, cg, cb, dp);
    P2[pidx] = make_float2(ac, T);
}

// 64 blocks x 256 thr: ordered combine of buckets + white background
__global__ __launch_bounds__(TPB) void gs_combine(
    const float4* __restrict__ P1, const float2* __restrict__ P2,
    float* __restrict__ out)
{
    const int tid = threadIdx.x;
    const int tile = blockIdx.x;
    const int h = (tile >> 3) * 16;
    const int w = (tile & 7) * 16;

    float Tpre = 1.0f, cr = 0.f, cg = 0.f, cb = 0.f, dp = 0.f, ac = 0.f;
#pragma unroll
    for (int s = 0; s < NSEGD; ++s) {
        const int idx = (s * 64 + tile) * TPB + tid;
        float4 p1 = P1[idx];
        float2 p2 = P2[idx];
        cr += Tpre * p1.x; cg += Tpre * p1.y; cb += Tpre * p1.z;
        dp += Tpre * p1.w; ac += Tpre * p2.x;
        Tpre *= p2.y;
    }

    cr += (1.0f - ac); cg += (1.0f - ac); cb += (1.0f - ac);

    const int pxi = tid & 15, pyi = tid >> 4;
    const int y = h + pyi, x = w + pxi;
    const int pix = y * 128 + x;
    out[pix*3 + 0] = cr;
    out[pix*3 + 1] = cg;
    out[pix*3 + 2] = cb;
    out[128*128*3 + pix] = dp;
    out[128*128*3 + 128*128 + pix] = ac;
}

extern "C" void kernel_launch(void* const* d_in, const int* in_sizes, int n_in,
                              void* d_out, int out_size, void* d_ws, size_t ws_size,
                              hipStream_t stream) {
    const float* means3D    = (const float*)d_in[0];
    const float* opacity    = (const float*)d_in[1];
    const float* scales     = (const float*)d_in[2];
    const float* rotations  = (const float*)d_in[3];
    const float* shs        = (const float*)d_in[4];
    const float* viewmatrix = (const float*)d_in[5];
    const float* projmatrix = (const float*)d_in[6];
    const float* camcenter  = (const float*)d_in[7];
    float* out = (float*)d_out;

    int N = in_sizes[0] / 3;   // 8192
    int nblk = (N + TPB - 1) / TPB;

    char* p = (char*)d_ws;
    float4* A = (float4*)p;          p += (size_t)NMAX * sizeof(float4);
    float4* B = (float4*)p;          p += (size_t)NMAX * sizeof(float4);
    float4* C = (float4*)p;          p += (size_t)NMAX * sizeof(float4);
    float4* D = (float4*)p;          p += (size_t)NMAX * sizeof(float4);
    float4* P1 = (float4*)p;         p += (size_t)NSEGD * 64 * TPB * sizeof(float4);
    float2* P2 = (float2*)p;         p += (size_t)NSEGD * 64 * TPB * sizeof(float2);
    unsigned* K = (unsigned*)p;      p += (size_t)NMAX * sizeof(unsigned);
    unsigned* MMpart = (unsigned*)p; p += (size_t)2 * nblk * sizeof(unsigned);

    gs_preprocess<<<nblk, TPB, 0, stream>>>(
        means3D, opacity, scales, rotations, shs, viewmatrix, projmatrix,
        camcenter, A, B, C, D, K, MMpart, N);

    gs_render<<<dim3(NSEGD, 64), TPB, 0, stream>>>(
        A, B, C, D, K, MMpart, P1, P2, N, nblk);

    gs_combine<<<64, TPB, 0, stream>>>(P1, P2, out);
}